// Round 9
// baseline (392.072 us; speedup 1.0000x reference)
//
#include <hip/hip_runtime.h>

#define NN 20000
#define NE 640000
#define NCH 8
#define HID 64
#define EDIM 32
#define ODIM 64

typedef __attribute__((ext_vector_type(8))) short bf16x8;
typedef __attribute__((ext_vector_type(4))) float f32x4;

__device__ __forceinline__ float b2f(unsigned short u) {
    unsigned v = ((unsigned)u) << 16;
    return __builtin_bit_cast(float, v);
}
__device__ __forceinline__ unsigned short f2b(float f) {   // RNE
    unsigned u = __builtin_bit_cast(unsigned, f);
    unsigned r = (u + 0x7fffu + ((u >> 16) & 1u)) >> 16;
    return (unsigned short)r;
}
__device__ __forceinline__ f32x4 mfma16(bf16x8 a, bf16x8 b, f32x4 c) {
    return __builtin_amdgcn_mfma_f32_16x16x32_bf16(a, b, c, 0, 0, 0);
}
// B-fragment: lane(g=l>>4, r=l&15) holds B[k0+8g+j][n0+r], W row-major [K][ldn]
__device__ __forceinline__ bf16x8 load_bfrag(const unsigned short* W, int ldn, int k0, int n0, int lane) {
    int g = lane >> 4, r = lane & 15;
    bf16x8 f;
#pragma unroll
    for (int j = 0; j < 8; ++j) f[j] = (short)W[(k0 + 8 * g + j) * ldn + n0 + r];
    return f;
}

// ---------------- weight cast fp32 -> bf16 (one shot) ----------------
__global__ __launch_bounds__(256) void k_prep(
    const float* We1, const float* We2, const float* W11, const float* W21,
    const float* W12, const float* W22, const float* W20, const float* Wr1,
    const float* Wr2, unsigned short* bw)
{
    int gid = blockIdx.x * 256 + threadIdx.x;
    const float* src; int off;
    if      (gid < 2048)  { src = We1; off = 0; }
    else if (gid < 4096)  { src = We2; off = 2048; }
    else if (gid < 8192)  { src = W11; off = 4096; }
    else if (gid < 12288) { src = W21; off = 8192; }
    else if (gid < 16384) { src = W12; off = 12288; }
    else if (gid < 18432) { src = W22; off = 16384; }
    else if (gid < 22528) { src = W20; off = 18432; }
    else if (gid < 24576) { src = Wr1; off = 22528; }
    else                  { src = Wr2; off = 24576; }
    bw[gid] = f2b(src[gid - off]);
}

// ---------------- CSR build: histogram + x transpose ----------------
__global__ __launch_bounds__(256) void k_hist(const int* __restrict__ ei, int* __restrict__ cnt,
                                              const float* __restrict__ x, float* __restrict__ xt)
{
    int e = blockIdx.x * 256 + threadIdx.x;
    if (e < NE) atomicAdd(&cnt[ei[NE + e]], 1);
    if (e < NN) {
        f32x4 v = {x[e], x[NN + e], x[2 * NN + e], x[3 * NN + e]};
        *(f32x4*)(xt + (size_t)e * 4) = v;
    }
}

__global__ __launch_bounds__(1024) void k_scan(const int* __restrict__ cnt,
                                               int* __restrict__ row, int* __restrict__ cursor)
{
    __shared__ int part[1024];
    int t = threadIdx.x;
    int base = t * 20;                  // 1024*20 = 20480 >= 20000
    int s = 0;
#pragma unroll
    for (int i = 0; i < 20; ++i) { int idx = base + i; if (idx < NN) s += cnt[idx]; }
    part[t] = s;
    __syncthreads();
    int v = s;
    for (int off = 1; off < 1024; off <<= 1) {
        int add = (t >= off) ? part[t - off] : 0;
        __syncthreads();
        v += add;
        part[t] = v;
        __syncthreads();
    }
    int run = v - s;
    for (int i = 0; i < 20; ++i) {
        int idx = base + i;
        if (idx < NN) { row[idx] = run; cursor[idx] = run; run += cnt[idx]; }
    }
    if (t == 1023) row[NN] = NE;
}

// ---------------- scatter + ea permute + layer-0 scalar embed (fused) ----------------
__global__ __launch_bounds__(256) void k_scatter2(
    const int* __restrict__ ei, int* __restrict__ cursor,
    const float* __restrict__ ea, const float* __restrict__ We0, const float* __restrict__ be0,
    int* __restrict__ srcp, unsigned short* __restrict__ eap, float* __restrict__ emb0)
{
    int e = blockIdx.x * 256 + threadIdx.x;
    if (e >= NE) return;
    int d = ei[NE + e];
    int pos = atomicAdd(&cursor[d], 1);
    srcp[pos] = ei[e];
    const f32x4* s4 = (const f32x4*)(ea + (size_t)e * 32);   // sequential-ish read
    float e0 = be0[0];
#pragma unroll
    for (int h = 0; h < 4; ++h) {
        f32x4 a = s4[2 * h], b = s4[2 * h + 1];
        bf16x8 o;
#pragma unroll
        for (int j = 0; j < 4; ++j) {
            e0 = fmaf(a[j], We0[h * 8 + j], e0);
            e0 = fmaf(b[j], We0[h * 8 + 4 + j], e0);
            o[j] = (short)f2b(a[j]);
            o[4 + j] = (short)f2b(b[j]);
        }
        *(bf16x8*)(eap + (size_t)pos * 32 + h * 8) = o;      // scattered 64B write
    }
    emb0[pos] = e0;
}

// ---------------- layer-0 gather: wave per 2 nodes, lanes stride edges ----------------
__global__ __launch_bounds__(256) void k_l0_gather(
    const float* __restrict__ xt, const int* __restrict__ srcp,
    const int* __restrict__ row, const float* __restrict__ emb0,
    float* __restrict__ z0)
{
    int gwave = (blockIdx.x * 256 + threadIdx.x) >> 6;
    int half = (threadIdx.x >> 5) & 1;
    int l = threadIdx.x & 31;
    int d = gwave * 2 + half;
    if (d >= NN) return;
    int p0 = row[d], p1 = row[d + 1];
    float ap0 = 0.f, ap1 = 0.f, ap2 = 0.f, ap3 = 0.f;
    float am0 = 0.f, am1 = 0.f, am2 = 0.f, am3 = 0.f;
    for (int p = p0 + l; p < p1; p += 32) {
        float e0 = emb0[p];
        f32x4 xs = *(const f32x4*)(xt + (size_t)srcp[p] * 4);
        ap0 += fmaxf(xs[0] + e0, 0.f); am0 += fmaxf(e0 - xs[0], 0.f);
        ap1 += fmaxf(xs[1] + e0, 0.f); am1 += fmaxf(e0 - xs[1], 0.f);
        ap2 += fmaxf(xs[2] + e0, 0.f); am2 += fmaxf(e0 - xs[2], 0.f);
        ap3 += fmaxf(xs[3] + e0, 0.f); am3 += fmaxf(e0 - xs[3], 0.f);
    }
#pragma unroll
    for (int off = 1; off < 32; off <<= 1) {
        ap0 += __shfl_xor(ap0, off, 64); am0 += __shfl_xor(am0, off, 64);
        ap1 += __shfl_xor(ap1, off, 64); am1 += __shfl_xor(am1, off, 64);
        ap2 += __shfl_xor(ap2, off, 64); am2 += __shfl_xor(am2, off, 64);
        ap3 += __shfl_xor(ap3, off, 64); am3 += __shfl_xor(am3, off, 64);
    }
    if (l == 0) {
        f32x4 xd = *(const f32x4*)(xt + (size_t)d * 4);
        f32x4 zp = {xd[0] + ap0, xd[1] + ap1, xd[2] + ap2, xd[3] + ap3};
        f32x4 zm = {am0 - xd[0], am1 - xd[1], am2 - xd[2], am3 - xd[3]};
        *(f32x4*)(z0 + (size_t)d * 8) = zp;
        *(f32x4*)(z0 + (size_t)d * 8 + 4) = zm;
    }
}

// ---------------- layer-0 MLP -> hT [node][feat][ch] ----------------
__global__ __launch_bounds__(256) void k_l0_mlp(
    const float* __restrict__ z0,
    const float* __restrict__ W1, const float* __restrict__ b1,
    const unsigned short* __restrict__ W2b, const float* __restrict__ b2,
    unsigned short* __restrict__ hT)
{
    constexpr int S = 72;
    __shared__ short lds[4][16 * S];
    int lane = threadIdx.x & 63, wid = threadIdx.x >> 6, g = lane >> 4, r = lane & 15;
    short* L = lds[wid];
    bf16x8 w2f[2][4];
#pragma unroll
    for (int kk = 0; kk < 2; ++kk)
#pragma unroll
        for (int t = 0; t < 4; ++t) w2f[kk][t] = load_bfrag(W2b, 64, kk * 32, t * 16, lane);
    float b2v[4];
#pragma unroll
    for (int t = 0; t < 4; ++t) b2v[t] = b2[t * 16 + r];
    float w1a[8], w1b[8], b1a[8], b1b[8];
#pragma unroll
    for (int j = 0; j < 8; ++j) {
        w1a[j] = W1[8 * g + j];      b1a[j] = b1[8 * g + j];
        w1b[j] = W1[32 + 8 * g + j]; b1b[j] = b1[32 + 8 * g + j];
    }
    int tile = blockIdx.x * 4 + wid;      // 10000 tiles
    int row0 = tile * 16;
    float zv = z0[row0 + r];
    bf16x8 a0, a1;
#pragma unroll
    for (int j = 0; j < 8; ++j) {
        a0[j] = (short)f2b(fmaxf(fmaf(zv, w1a[j], b1a[j]), 0.f));
        a1[j] = (short)f2b(fmaxf(fmaf(zv, w1b[j], b1b[j]), 0.f));
    }
    f32x4 c2[4];
#pragma unroll
    for (int t = 0; t < 4; ++t) {
        f32x4 c = {0.f, 0.f, 0.f, 0.f};
        c = mfma16(a0, w2f[0][t], c);
        c = mfma16(a1, w2f[1][t], c);
        c2[t] = c;
    }
#pragma unroll
    for (int t = 0; t < 4; ++t)
#pragma unroll
        for (int i = 0; i < 4; ++i)
            L[(4 * g + i) * S + t * 16 + r] = (short)f2b(fmaxf(c2[t][i] + b2v[t], 0.f));
    asm volatile("" ::: "memory");
    int node0 = tile * 2;
#pragma unroll
    for (int half = 0; half < 2; ++half) {
        bf16x8 v;
#pragma unroll
        for (int c = 0; c < 8; ++c) v[c] = L[(half * 8 + c) * S + lane];
        *(bf16x8*)(hT + (size_t)(node0 + half) * 512 + lane * 8) = v;
    }
}

// ---------------- fused gather + node MLP ----------------
// Block = 4 waves = 4 dst nodes = 32 MLP rows. Gather (R8-proven core) -> LDS stage
// -> 2 row-tiles x 2 col-halves MFMA MLP -> write hT2 / h2 directly.
template <int OUT>
__global__ __launch_bounds__(256) void k_gather_mlp(
    const int* __restrict__ srcp, const int* __restrict__ row,
    const unsigned short* __restrict__ eap,
    const unsigned short* __restrict__ Web, const float* __restrict__ be,
    const unsigned short* __restrict__ W1b, const float* __restrict__ b1,
    const unsigned short* __restrict__ W2b, const float* __restrict__ b2,
    const unsigned short* __restrict__ hin, unsigned short* __restrict__ hout)
{
    constexpr int S4 = 66;
    constexpr int SZ = 80;                 // staging row stride (shorts), 160B = 16B-mult
    __shared__ float smem[4 * 16 * S4];    // 16896 B; overlaid: emb tiles, then Lz/Lt
    int lane = threadIdx.x & 63, wid = threadIdx.x >> 6, g = lane >> 4, r = lane & 15;
    float* L = smem + wid * 16 * S4;
    short* Lz = (short*)smem;              // [32][SZ]
    short* Lt = Lz + 32 * SZ;              // [32][SZ]

    bf16x8 wf[4];
#pragma unroll
    for (int t = 0; t < 4; ++t) wf[t] = load_bfrag(Web, 64, 0, t * 16, lane);
    float bev[4];
#pragma unroll
    for (int t = 0; t < 4; ++t) bev[t] = be[t * 16 + r];

    int d = blockIdx.x * 4 + wid;     // 5000 blocks x 4 waves = 20000
    int p0 = row[d], p1 = row[d + 1];
    float acc[NCH];
#pragma unroll
    for (int c = 0; c < NCH; ++c) acc[c] = 0.f;

    for (int p = p0; p < p1; p += 16) {
        int ne = p1 - p; if (ne > 16) ne = 16;
        int pp = p + r; if (pp > p1 - 1) pp = p1 - 1;
        bf16x8 afc = *(const bf16x8*)(eap + (size_t)pp * 32 + 8 * g);
        int svc = srcp[pp];
        f32x4 c[4];
#pragma unroll
        for (int t = 0; t < 4; ++t) {
            f32x4 cc = {bev[t], bev[t], bev[t], bev[t]};
            c[t] = mfma16(afc, wf[t], cc);
        }
#pragma unroll
        for (int t = 0; t < 4; ++t)
#pragma unroll
            for (int i = 0; i < 4; ++i) {
                float v = (4 * g + i < ne) ? c[t][i] : -__builtin_inff();
                L[(4 * g + i) * S4 + t * 16 + r] = v;
            }
        asm volatile("" ::: "memory");
#pragma unroll
        for (int b = 0; b < 4; ++b) {
#pragma unroll
            for (int q = 4 * b; q < 4 * b + 4; ++q) {
                int src = __builtin_amdgcn_readlane(svc, q);
                float em = L[q * S4 + lane];
                uint4 hv = *(const uint4*)(hin + (size_t)src * 512 + (lane << 3));
                acc[0] += fmaxf(__builtin_bit_cast(float, hv.x << 16) + em, 0.f);
                acc[1] += fmaxf(__builtin_bit_cast(float, hv.x & 0xffff0000u) + em, 0.f);
                acc[2] += fmaxf(__builtin_bit_cast(float, hv.y << 16) + em, 0.f);
                acc[3] += fmaxf(__builtin_bit_cast(float, hv.y & 0xffff0000u) + em, 0.f);
                acc[4] += fmaxf(__builtin_bit_cast(float, hv.z << 16) + em, 0.f);
                acc[5] += fmaxf(__builtin_bit_cast(float, hv.z & 0xffff0000u) + em, 0.f);
                acc[6] += fmaxf(__builtin_bit_cast(float, hv.w << 16) + em, 0.f);
                acc[7] += fmaxf(__builtin_bit_cast(float, hv.w & 0xffff0000u) + em, 0.f);
            }
            __builtin_amdgcn_sched_barrier(0);
        }
        asm volatile("" ::: "memory");
    }

    // z = h_dst + acc (fp32), held per-lane(=feat), reg=ch
    uint4 hd = *(const uint4*)(hin + (size_t)d * 512 + (lane << 3));
    float zval[8];
    {
        unsigned hw[4] = {hd.x, hd.y, hd.z, hd.w};
#pragma unroll
        for (int j = 0; j < 4; ++j) {
            zval[2 * j]     = __builtin_bit_cast(float, hw[j] << 16) + acc[2 * j];
            zval[2 * j + 1] = __builtin_bit_cast(float, hw[j] & 0xffff0000u) + acc[2 * j + 1];
        }
    }

    // ---- MLP phase: all waves must be done with emb region before overlay ----
    __syncthreads();
#pragma unroll
    for (int c = 0; c < 8; ++c)
        Lz[(wid * 8 + c) * SZ + lane] = (short)f2b(zval[c]);
    __syncthreads();

    int t = wid >> 1;          // row tile (0..1), rows t*16..t*16+15
    int nh = wid & 1;          // column half
    // GEMM1: cols [nh*32, nh*32+32)
    bf16x8 w1f[2][2];
#pragma unroll
    for (int kk = 0; kk < 2; ++kk)
#pragma unroll
        for (int nt = 0; nt < 2; ++nt)
            w1f[kk][nt] = load_bfrag(W1b, 64, kk * 32, nh * 32 + nt * 16, lane);
    bf16x8 a0 = *(const bf16x8*)(Lz + (t * 16 + r) * SZ + 8 * g);
    bf16x8 a1 = *(const bf16x8*)(Lz + (t * 16 + r) * SZ + 32 + 8 * g);
#pragma unroll
    for (int nt = 0; nt < 2; ++nt) {
        float bb = b1[nh * 32 + nt * 16 + r];
        f32x4 cc = {bb, bb, bb, bb};
        cc = mfma16(a0, w1f[0][nt], cc);
        cc = mfma16(a1, w1f[1][nt], cc);
#pragma unroll
        for (int i = 0; i < 4; ++i)
            Lt[(t * 16 + 4 * g + i) * SZ + nh * 32 + nt * 16 + r] = (short)f2b(fmaxf(cc[i], 0.f));
    }
    __syncthreads();

    // GEMM2
    bf16x8 t0 = *(const bf16x8*)(Lt + (t * 16 + r) * SZ + 8 * g);
    bf16x8 t1 = *(const bf16x8*)(Lt + (t * 16 + r) * SZ + 32 + 8 * g);
    if (OUT == 64) {
#pragma unroll
        for (int nt = 0; nt < 2; ++nt) {
            float bb = b2[nh * 32 + nt * 16 + r];
            f32x4 cc = {bb, bb, bb, bb};
            cc = mfma16(t0, load_bfrag(W2b, 64, 0, nh * 32 + nt * 16, lane), cc);
            cc = mfma16(t1, load_bfrag(W2b, 64, 32, nh * 32 + nt * 16, lane), cc);
#pragma unroll
            for (int i = 0; i < 4; ++i)     // inter-layer relu
                Lz[(t * 16 + 4 * g + i) * SZ + nh * 32 + nt * 16 + r] = (short)f2b(fmaxf(cc[i], 0.f));
        }
        __syncthreads();
        // write hT2 [node][feat(64)][ch(8)]
        bf16x8 v;
#pragma unroll
        for (int c = 0; c < 8; ++c) v[c] = Lz[(wid * 8 + c) * SZ + lane];
        *(bf16x8*)(hout + (size_t)d * 512 + lane * 8) = v;
    } else {
        // OUT=32: wave covers 16 cols at nh*16
        float bb = b2[nh * 16 + r];
        f32x4 cc = {bb, bb, bb, bb};
        cc = mfma16(t0, load_bfrag(W2b, 32, 0, nh * 16, lane), cc);
        cc = mfma16(t1, load_bfrag(W2b, 32, 32, nh * 16, lane), cc);
#pragma unroll
        for (int i = 0; i < 4; ++i)         // no relu (last phi layer)
            Lz[(t * 16 + 4 * g + i) * SZ + nh * 16 + r] = (short)f2b(cc[i]);
        __syncthreads();
        // write h2 rows [node*8+ch][32]
        int r8 = lane >> 3;                 // ch
        int cg = (lane & 7) * 4;            // col group of 4
        short o[4];
#pragma unroll
        for (int j = 0; j < 4; ++j) o[j] = Lz[(wid * 8 + r8) * SZ + cg + j];
        *(short4*)(hout + ((size_t)d * 8 + r8) * 32 + cg) = make_short4(o[0], o[1], o[2], o[3]);
    }
}

// ---------------- rho: pool channels + 2-GEMM MLP, fp32 out ----------------
__global__ __launch_bounds__(256) void k_rho(
    const unsigned short* __restrict__ h2,
    const unsigned short* __restrict__ Wr1b, const float* __restrict__ br1,
    const unsigned short* __restrict__ Wr2b, const float* __restrict__ br2,
    float* __restrict__ out)
{
    constexpr int S = 72;
    __shared__ short lds[4][16 * S];
    int lane = threadIdx.x & 63, wid = threadIdx.x >> 6, g = lane >> 4, r = lane & 15;
    short* L = lds[wid];
    int tile = blockIdx.x * 4 + wid;      // 1250 tiles
    if (tile * 16 >= NN) return;
    bf16x8 w1f[4], w2f[2][4];
#pragma unroll
    for (int t = 0; t < 4; ++t) w1f[t] = load_bfrag(Wr1b, 64, 0, t * 16, lane);
#pragma unroll
    for (int kk = 0; kk < 2; ++kk)
#pragma unroll
        for (int t = 0; t < 4; ++t) w2f[kk][t] = load_bfrag(Wr2b, 64, kk * 32, t * 16, lane);
    float b1v[4], b2v[4];
#pragma unroll
    for (int t = 0; t < 4; ++t) { b1v[t] = br1[t * 16 + r]; b2v[t] = br2[t * 16 + r]; }

    int n = tile * 16 + r;
    float s[8] = {0.f, 0.f, 0.f, 0.f, 0.f, 0.f, 0.f, 0.f};
#pragma unroll
    for (int c = 0; c < NCH; ++c) {
        bf16x8 hv = *(const bf16x8*)(h2 + ((size_t)n * 8 + c) * 32 + 8 * g);
#pragma unroll
        for (int j = 0; j < 8; ++j) s[j] += b2f((unsigned short)hv[j]);
    }
    bf16x8 af;
#pragma unroll
    for (int j = 0; j < 8; ++j) af[j] = (short)f2b(s[j]);
    f32x4 c1[4];
#pragma unroll
    for (int t = 0; t < 4; ++t) {
        f32x4 c = {0.f, 0.f, 0.f, 0.f};
        c1[t] = mfma16(af, w1f[t], c);
    }
#pragma unroll
    for (int t = 0; t < 4; ++t)
#pragma unroll
        for (int i = 0; i < 4; ++i)
            L[(4 * g + i) * S + t * 16 + r] = (short)f2b(fmaxf(c1[t][i] + b1v[t], 0.f));
    asm volatile("" ::: "memory");
    bf16x8 t0 = *(const bf16x8*)(L + r * S + 8 * g);
    bf16x8 t1 = *(const bf16x8*)(L + r * S + 32 + 8 * g);
    f32x4 c2[4];
#pragma unroll
    for (int t = 0; t < 4; ++t) {
        f32x4 c = {0.f, 0.f, 0.f, 0.f};
        c = mfma16(t0, w2f[0][t], c);
        c = mfma16(t1, w2f[1][t], c);
        c2[t] = c;
    }
    int nb = tile * 16;
#pragma unroll
    for (int t = 0; t < 4; ++t)
#pragma unroll
        for (int i = 0; i < 4; ++i)
            out[(size_t)(nb + 4 * g + i) * 64 + t * 16 + r] = c2[t][i] + b2v[t];
}

extern "C" void kernel_launch(void* const* d_in, const int* in_sizes, int n_in,
                              void* d_out, int out_size, void* d_ws, size_t ws_size,
                              hipStream_t stream)
{
    const float* x   = (const float*)d_in[0];
    const float* ea  = (const float*)d_in[1];
    const int*   ei  = (const int*)d_in[2];
    const float* We0 = (const float*)d_in[3];
    const float* be0 = (const float*)d_in[4];
    const float* W10 = (const float*)d_in[5];
    const float* b10 = (const float*)d_in[6];
    const float* W20 = (const float*)d_in[7];
    const float* b20 = (const float*)d_in[8];
    const float* We1 = (const float*)d_in[9];
    const float* be1 = (const float*)d_in[10];
    const float* W11 = (const float*)d_in[11];
    const float* b11 = (const float*)d_in[12];
    const float* W21 = (const float*)d_in[13];
    const float* b21 = (const float*)d_in[14];
    const float* We2 = (const float*)d_in[15];
    const float* be2 = (const float*)d_in[16];
    const float* W12 = (const float*)d_in[17];
    const float* b12 = (const float*)d_in[18];
    const float* W22 = (const float*)d_in[19];
    const float* b22 = (const float*)d_in[20];
    const float* Wr1 = (const float*)d_in[21];
    const float* br1 = (const float*)d_in[22];
    const float* Wr2 = (const float*)d_in[23];
    const float* br2 = (const float*)d_in[24];
    float* out = (float*)d_out;

    // ---- workspace layout (128B-aligned blocks) ----
    char* base = (char*)d_ws;
    unsigned short* hT   = (unsigned short*)base; base += (size_t)NN * 512 * 2;        // 20.48 MB
    unsigned short* hT2  = (unsigned short*)base; base += (size_t)NN * 512 * 2;        // 20.48 MB
    unsigned short* h2   = (unsigned short*)base; base += (size_t)160000 * 32 * 2;     // 10.24 MB
    unsigned short* eap  = (unsigned short*)base; base += (size_t)NE * 32 * 2;         // 40.96 MB
    float* emb0          = (float*)base;          base += (size_t)NE * 4;              //  2.56 MB
    float* z0            = (float*)base;          base += (size_t)160000 * 4;          //  0.64 MB
    float* xt            = (float*)base;          base += (size_t)NN * 4 * 4;          //  0.32 MB
    int* srcp            = (int*)base;            base += (size_t)NE * 4;              //  2.56 MB
    int* row             = (int*)base;            base += 80128;
    int* cnt             = (int*)base;            base += 80128;
    int* cursor          = (int*)base;            base += 80128;
    unsigned short* bw   = (unsigned short*)base;                                      // 57 KB

    const unsigned short* bWe1 = bw;
    const unsigned short* bWe2 = bw + 2048;
    const unsigned short* bW11 = bw + 4096;
    const unsigned short* bW21 = bw + 8192;
    const unsigned short* bW12 = bw + 12288;
    const unsigned short* bW22 = bw + 16384;
    const unsigned short* bW20 = bw + 18432;
    const unsigned short* bWr1 = bw + 22528;
    const unsigned short* bWr2 = bw + 24576;

    // ---- prep ----
    k_prep<<<112, 256, 0, stream>>>(We1, We2, W11, W21, W12, W22, W20, Wr1, Wr2, bw);
    hipMemsetAsync(cnt, 0, NN * sizeof(int), stream);
    k_hist<<<NE / 256, 256, 0, stream>>>(ei, cnt, x, xt);
    k_scan<<<1, 1024, 0, stream>>>(cnt, row, cursor);
    k_scatter2<<<NE / 256, 256, 0, stream>>>(ei, cursor, ea, We0, be0, srcp, eap, emb0);

    // ---- layer 0 ----
    k_l0_gather<<<(NN / 2 + 3) / 4, 256, 0, stream>>>(xt, srcp, row, emb0, z0);
    k_l0_mlp<<<2500, 256, 0, stream>>>(z0, W10, b10, bW20, b20, hT);

    // ---- layer 1 (gather + MLP fused; read hT, write hT2) ----
    k_gather_mlp<64><<<NN / 4, 256, 0, stream>>>(srcp, row, eap, bWe1, be1,
                                                 bW11, b11, bW21, b21, hT, hT2);

    // ---- layer 2 (read hT2, write h2) ----
    k_gather_mlp<32><<<NN / 4, 256, 0, stream>>>(srcp, row, eap, bWe2, be2,
                                                 bW12, b12, bW22, b22, hT2, h2);

    // ---- pool + rho ----
    k_rho<<<313, 256, 0, stream>>>(h2, bWr1, br1, bWr2, br2, out);
}

// Round 10
// 358.088 us; speedup vs baseline: 1.0949x; 1.0949x over previous
//
#include <hip/hip_runtime.h>

#define NN 20000
#define NE 640000
#define NCH 8
#define HID 64
#define EDIM 32
#define ODIM 64

typedef __attribute__((ext_vector_type(8))) short bf16x8;
typedef __attribute__((ext_vector_type(4))) float f32x4;

__device__ __forceinline__ float b2f(unsigned short u) {
    unsigned v = ((unsigned)u) << 16;
    return __builtin_bit_cast(float, v);
}
__device__ __forceinline__ unsigned short f2b(float f) {   // RNE
    unsigned u = __builtin_bit_cast(unsigned, f);
    unsigned r = (u + 0x7fffu + ((u >> 16) & 1u)) >> 16;
    return (unsigned short)r;
}
__device__ __forceinline__ f32x4 mfma16(bf16x8 a, bf16x8 b, f32x4 c) {
    return __builtin_amdgcn_mfma_f32_16x16x32_bf16(a, b, c, 0, 0, 0);
}
// B-fragment: lane(g=l>>4, r=l&15) holds B[k0+8g+j][n0+r], W row-major [K][ldn]
__device__ __forceinline__ bf16x8 load_bfrag(const unsigned short* W, int ldn, int k0, int n0, int lane) {
    int g = lane >> 4, r = lane & 15;
    bf16x8 f;
#pragma unroll
    for (int j = 0; j < 8; ++j) f[j] = (short)W[(k0 + 8 * g + j) * ldn + n0 + r];
    return f;
}

// ---------------- weight cast fp32 -> bf16 (one shot) ----------------
__global__ __launch_bounds__(256) void k_prep(
    const float* We1, const float* We2, const float* W11, const float* W21,
    const float* W12, const float* W22, const float* W20, const float* Wr1,
    const float* Wr2, unsigned short* bw)
{
    int gid = blockIdx.x * 256 + threadIdx.x;
    const float* src; int off;
    if      (gid < 2048)  { src = We1; off = 0; }
    else if (gid < 4096)  { src = We2; off = 2048; }
    else if (gid < 8192)  { src = W11; off = 4096; }
    else if (gid < 12288) { src = W21; off = 8192; }
    else if (gid < 16384) { src = W12; off = 12288; }
    else if (gid < 18432) { src = W22; off = 16384; }
    else if (gid < 22528) { src = W20; off = 18432; }
    else if (gid < 24576) { src = Wr1; off = 22528; }
    else                  { src = Wr2; off = 24576; }
    bw[gid] = f2b(src[gid - off]);
}

// ---------------- CSR build: histogram + x transpose ----------------
__global__ __launch_bounds__(256) void k_hist(const int* __restrict__ ei, int* __restrict__ cnt,
                                              const float* __restrict__ x, float* __restrict__ xt)
{
    int e = blockIdx.x * 256 + threadIdx.x;
    if (e < NE) atomicAdd(&cnt[ei[NE + e]], 1);
    if (e < NN) {
        f32x4 v = {x[e], x[NN + e], x[2 * NN + e], x[3 * NN + e]};
        *(f32x4*)(xt + (size_t)e * 4) = v;
    }
}

__global__ __launch_bounds__(1024) void k_scan(const int* __restrict__ cnt,
                                               int* __restrict__ row, int* __restrict__ cursor)
{
    __shared__ int part[1024];
    int t = threadIdx.x;
    int base = t * 20;                  // 1024*20 = 20480 >= 20000
    int s = 0;
#pragma unroll
    for (int i = 0; i < 20; ++i) { int idx = base + i; if (idx < NN) s += cnt[idx]; }
    part[t] = s;
    __syncthreads();
    int v = s;
    for (int off = 1; off < 1024; off <<= 1) {
        int add = (t >= off) ? part[t - off] : 0;
        __syncthreads();
        v += add;
        part[t] = v;
        __syncthreads();
    }
    int run = v - s;
    for (int i = 0; i < 20; ++i) {
        int idx = base + i;
        if (idx < NN) { row[idx] = run; cursor[idx] = run; run += cnt[idx]; }
    }
    if (t == 1023) row[NN] = NE;
}

// ---------------- scatter + ea permute + layer-0 scalar embed (fused) ----------------
__global__ __launch_bounds__(256) void k_scatter2(
    const int* __restrict__ ei, int* __restrict__ cursor,
    const float* __restrict__ ea, const float* __restrict__ We0, const float* __restrict__ be0,
    int* __restrict__ srcp, unsigned short* __restrict__ eap, float* __restrict__ emb0)
{
    int e = blockIdx.x * 256 + threadIdx.x;
    if (e >= NE) return;
    int d = ei[NE + e];
    int pos = atomicAdd(&cursor[d], 1);
    srcp[pos] = ei[e];
    const f32x4* s4 = (const f32x4*)(ea + (size_t)e * 32);   // sequential read
    float e0 = be0[0];
#pragma unroll
    for (int h = 0; h < 4; ++h) {
        f32x4 a = s4[2 * h], b = s4[2 * h + 1];
        bf16x8 o;
#pragma unroll
        for (int j = 0; j < 4; ++j) {
            e0 = fmaf(a[j], We0[h * 8 + j], e0);
            e0 = fmaf(b[j], We0[h * 8 + 4 + j], e0);
            o[j] = (short)f2b(a[j]);
            o[4 + j] = (short)f2b(b[j]);
        }
        *(bf16x8*)(eap + (size_t)pos * 32 + h * 8) = o;      // scattered 64B write
    }
    emb0[pos] = e0;
}

// ---------------- layer-0 gather: wave per 2 nodes, lanes stride edges ----------------
__global__ __launch_bounds__(256) void k_l0_gather(
    const float* __restrict__ xt, const int* __restrict__ srcp,
    const int* __restrict__ row, const float* __restrict__ emb0,
    float* __restrict__ z0)
{
    int gwave = (blockIdx.x * 256 + threadIdx.x) >> 6;
    int half = (threadIdx.x >> 5) & 1;
    int l = threadIdx.x & 31;
    int d = gwave * 2 + half;
    if (d >= NN) return;
    int p0 = row[d], p1 = row[d + 1];
    float ap0 = 0.f, ap1 = 0.f, ap2 = 0.f, ap3 = 0.f;
    float am0 = 0.f, am1 = 0.f, am2 = 0.f, am3 = 0.f;
    for (int p = p0 + l; p < p1; p += 32) {
        float e0 = emb0[p];
        f32x4 xs = *(const f32x4*)(xt + (size_t)srcp[p] * 4);
        ap0 += fmaxf(xs[0] + e0, 0.f); am0 += fmaxf(e0 - xs[0], 0.f);
        ap1 += fmaxf(xs[1] + e0, 0.f); am1 += fmaxf(e0 - xs[1], 0.f);
        ap2 += fmaxf(xs[2] + e0, 0.f); am2 += fmaxf(e0 - xs[2], 0.f);
        ap3 += fmaxf(xs[3] + e0, 0.f); am3 += fmaxf(e0 - xs[3], 0.f);
    }
#pragma unroll
    for (int off = 1; off < 32; off <<= 1) {
        ap0 += __shfl_xor(ap0, off, 64); am0 += __shfl_xor(am0, off, 64);
        ap1 += __shfl_xor(ap1, off, 64); am1 += __shfl_xor(am1, off, 64);
        ap2 += __shfl_xor(ap2, off, 64); am2 += __shfl_xor(am2, off, 64);
        ap3 += __shfl_xor(ap3, off, 64); am3 += __shfl_xor(am3, off, 64);
    }
    if (l == 0) {
        f32x4 xd = *(const f32x4*)(xt + (size_t)d * 4);
        f32x4 zp = {xd[0] + ap0, xd[1] + ap1, xd[2] + ap2, xd[3] + ap3};
        f32x4 zm = {am0 - xd[0], am1 - xd[1], am2 - xd[2], am3 - xd[3]};
        *(f32x4*)(z0 + (size_t)d * 8) = zp;
        *(f32x4*)(z0 + (size_t)d * 8 + 4) = zm;
    }
}

// ---------------- layer-0 MLP -> hT [node][feat][ch] ----------------
__global__ __launch_bounds__(256) void k_l0_mlp(
    const float* __restrict__ z0,
    const float* __restrict__ W1, const float* __restrict__ b1,
    const unsigned short* __restrict__ W2b, const float* __restrict__ b2,
    unsigned short* __restrict__ hT)
{
    constexpr int S = 72;
    __shared__ short lds[4][16 * S];
    int lane = threadIdx.x & 63, wid = threadIdx.x >> 6, g = lane >> 4, r = lane & 15;
    short* L = lds[wid];
    bf16x8 w2f[2][4];
#pragma unroll
    for (int kk = 0; kk < 2; ++kk)
#pragma unroll
        for (int t = 0; t < 4; ++t) w2f[kk][t] = load_bfrag(W2b, 64, kk * 32, t * 16, lane);
    float b2v[4];
#pragma unroll
    for (int t = 0; t < 4; ++t) b2v[t] = b2[t * 16 + r];
    float w1a[8], w1b[8], b1a[8], b1b[8];
#pragma unroll
    for (int j = 0; j < 8; ++j) {
        w1a[j] = W1[8 * g + j];      b1a[j] = b1[8 * g + j];
        w1b[j] = W1[32 + 8 * g + j]; b1b[j] = b1[32 + 8 * g + j];
    }
    int tile = blockIdx.x * 4 + wid;      // 10000 tiles
    int row0 = tile * 16;
    float zv = z0[row0 + r];
    bf16x8 a0, a1;
#pragma unroll
    for (int j = 0; j < 8; ++j) {
        a0[j] = (short)f2b(fmaxf(fmaf(zv, w1a[j], b1a[j]), 0.f));
        a1[j] = (short)f2b(fmaxf(fmaf(zv, w1b[j], b1b[j]), 0.f));
    }
    f32x4 c2[4];
#pragma unroll
    for (int t = 0; t < 4; ++t) {
        f32x4 c = {0.f, 0.f, 0.f, 0.f};
        c = mfma16(a0, w2f[0][t], c);
        c = mfma16(a1, w2f[1][t], c);
        c2[t] = c;
    }
#pragma unroll
    for (int t = 0; t < 4; ++t)
#pragma unroll
        for (int i = 0; i < 4; ++i)
            L[(4 * g + i) * S + t * 16 + r] = (short)f2b(fmaxf(c2[t][i] + b2v[t], 0.f));
    asm volatile("" ::: "memory");
    int node0 = tile * 2;
#pragma unroll
    for (int half = 0; half < 2; ++half) {
        bf16x8 v;
#pragma unroll
        for (int c = 0; c < 8; ++c) v[c] = L[(half * 8 + c) * S + lane];
        *(bf16x8*)(hT + (size_t)(node0 + half) * 512 + lane * 8) = v;
    }
}

// ---------------- fused gather: We fragments staged in LDS (low VGPR), 4-deep batches ----------------
__global__ __launch_bounds__(256) void k_gather_f(
    const int* __restrict__ srcp, const int* __restrict__ row,
    const unsigned short* __restrict__ eap,
    const unsigned short* __restrict__ Web, const float* __restrict__ be,
    const unsigned short* __restrict__ hT, unsigned short* __restrict__ z)
{
    constexpr int SE = 66;                  // em tile stride (shorts)
    __shared__ short Lw[4 * 64 * 8];        // fragmentized We: tile t, lane l -> 8 shorts
    __shared__ short Lem[4][16 * SE];       // per-wave em tile (bf16)
    int lane = threadIdx.x & 63, wid = threadIdx.x >> 6, g = lane >> 4, r = lane & 15;
    short* Le = Lem[wid];

    // stage We fragments once per block: wave wid handles tile wid
    {
        bf16x8 f = load_bfrag(Web, 64, 0, wid * 16, lane);
        *(bf16x8*)(Lw + (wid * 64 + lane) * 8) = f;
    }
    float bev[4];
#pragma unroll
    for (int t = 0; t < 4; ++t) bev[t] = be[t * 16 + r];
    __syncthreads();

    int d = blockIdx.x * 4 + wid;     // 5000 blocks x 4 waves = 20000
    int p0 = row[d], p1 = row[d + 1];
    float acc[NCH];
#pragma unroll
    for (int c = 0; c < NCH; ++c) acc[c] = 0.f;

    for (int p = p0; p < p1; p += 16) {
        int ne = p1 - p; if (ne > 16) ne = 16;
        int pp = p + r; if (pp > p1 - 1) pp = p1 - 1;
        bf16x8 afc = *(const bf16x8*)(eap + (size_t)pp * 32 + 8 * g);
        int svc = srcp[pp];
        // em tile: one MFMA sub-tile at a time (1 W-fragment live; re-read from LDS
        // each iteration — the in-loop memory fences block cross-iteration caching)
#pragma unroll
        for (int t = 0; t < 4; ++t) {
            bf16x8 wfrag = *(const bf16x8*)(Lw + (t * 64 + lane) * 8);
            f32x4 cc = {bev[t], bev[t], bev[t], bev[t]};
            cc = mfma16(afc, wfrag, cc);
#pragma unroll
            for (int i = 0; i < 4; ++i) {
                unsigned short v = (4 * g + i < ne) ? f2b(cc[i]) : (unsigned short)0xFF80; // bf16 -inf
                Le[(4 * g + i) * SE + t * 16 + r] = (short)v;
            }
        }
        asm volatile("" ::: "memory");
        // four 4-deep batches: 4 uint4 loads (16 VGPR) in flight at once
#pragma unroll
        for (int b = 0; b < 4; ++b) {
#pragma unroll
            for (int q = 4 * b; q < 4 * b + 4; ++q) {
                int src = __builtin_amdgcn_readlane(svc, q);
                float em = b2f((unsigned short)Le[q * SE + lane]);
                uint4 hv = *(const uint4*)(hT + (size_t)src * 512 + (lane << 3));
                acc[0] += fmaxf(__builtin_bit_cast(float, hv.x << 16) + em, 0.f);
                acc[1] += fmaxf(__builtin_bit_cast(float, hv.x & 0xffff0000u) + em, 0.f);
                acc[2] += fmaxf(__builtin_bit_cast(float, hv.y << 16) + em, 0.f);
                acc[3] += fmaxf(__builtin_bit_cast(float, hv.y & 0xffff0000u) + em, 0.f);
                acc[4] += fmaxf(__builtin_bit_cast(float, hv.z << 16) + em, 0.f);
                acc[5] += fmaxf(__builtin_bit_cast(float, hv.z & 0xffff0000u) + em, 0.f);
                acc[6] += fmaxf(__builtin_bit_cast(float, hv.w << 16) + em, 0.f);
                acc[7] += fmaxf(__builtin_bit_cast(float, hv.w & 0xffff0000u) + em, 0.f);
            }
            __builtin_amdgcn_sched_barrier(0);
        }
        asm volatile("" ::: "memory");
    }

    // epilogue: z = h_dst + acc
    uint4 hd = *(const uint4*)(hT + (size_t)d * 512 + (lane << 3));
    unsigned hw[4] = {hd.x, hd.y, hd.z, hd.w};
    unsigned short* zd = z + (size_t)d * 8 * 64 + lane;
#pragma unroll
    for (int j = 0; j < 4; ++j) {
        float lo = __builtin_bit_cast(float, hw[j] << 16);
        float hi = __builtin_bit_cast(float, hw[j] & 0xffff0000u);
        zd[(2 * j) * 64] = f2b(lo + acc[2 * j]);
        zd[(2 * j + 1) * 64] = f2b(hi + acc[2 * j + 1]);
    }
}

// ---------------- node MLP: z -> (hT | h2-rows) ----------------
template <int OUT, bool RELU2, bool TOHT>
__global__ __launch_bounds__(256) void k_mlp(
    const unsigned short* __restrict__ z,
    const unsigned short* __restrict__ W1b, const float* __restrict__ b1,
    const unsigned short* __restrict__ W2b, const float* __restrict__ b2,
    unsigned short* __restrict__ hout)
{
    constexpr int S1 = 72;
    constexpr int S2 = (OUT == 64) ? 72 : 40;
    constexpr int NT2 = OUT / 16;
    __shared__ short lds[4][16 * S1];
    int lane = threadIdx.x & 63, wid = threadIdx.x >> 6, g = lane >> 4, r = lane & 15;
    short* L = lds[wid];

    bf16x8 w1f[2][4];
#pragma unroll
    for (int kk = 0; kk < 2; ++kk)
#pragma unroll
        for (int t = 0; t < 4; ++t) w1f[kk][t] = load_bfrag(W1b, 64, kk * 32, t * 16, lane);
    bf16x8 w2f[2][NT2];
#pragma unroll
    for (int kk = 0; kk < 2; ++kk)
#pragma unroll
        for (int t = 0; t < NT2; ++t) w2f[kk][t] = load_bfrag(W2b, OUT, kk * 32, t * 16, lane);
    float b1v[4], b2v[NT2];
#pragma unroll
    for (int t = 0; t < 4; ++t) b1v[t] = b1[t * 16 + r];
#pragma unroll
    for (int t = 0; t < NT2; ++t) b2v[t] = b2[t * 16 + r];

    int tile = blockIdx.x * 4 + wid;      // 10000 tiles
    int row0 = tile * 16;

    bf16x8 a0 = *(const bf16x8*)(z + (size_t)(row0 + r) * 64 + 8 * g);
    bf16x8 a1 = *(const bf16x8*)(z + (size_t)(row0 + r) * 64 + 32 + 8 * g);
    f32x4 c1[4];
#pragma unroll
    for (int t = 0; t < 4; ++t) {
        f32x4 c = {0.f, 0.f, 0.f, 0.f};
        c = mfma16(a0, w1f[0][t], c);
        c = mfma16(a1, w1f[1][t], c);
        c1[t] = c;
    }
#pragma unroll
    for (int t = 0; t < 4; ++t)
#pragma unroll
        for (int i = 0; i < 4; ++i)
            L[(4 * g + i) * S1 + t * 16 + r] = (short)f2b(fmaxf(c1[t][i] + b1v[t], 0.f));
    asm volatile("" ::: "memory");
    bf16x8 t0 = *(const bf16x8*)(L + r * S1 + 8 * g);
    bf16x8 t1 = *(const bf16x8*)(L + r * S1 + 32 + 8 * g);
    f32x4 c2[NT2];
#pragma unroll
    for (int t = 0; t < NT2; ++t) {
        f32x4 c = {0.f, 0.f, 0.f, 0.f};
        c = mfma16(t0, w2f[0][t], c);
        c = mfma16(t1, w2f[1][t], c);
        c2[t] = c;
    }
    asm volatile("" ::: "memory");
#pragma unroll
    for (int t = 0; t < NT2; ++t)
#pragma unroll
        for (int i = 0; i < 4; ++i) {
            float v = c2[t][i] + b2v[t];
            if (RELU2) v = fmaxf(v, 0.f);
            L[(4 * g + i) * S2 + t * 16 + r] = (short)f2b(v);
        }
    asm volatile("" ::: "memory");
    if (TOHT) {
        int node0 = tile * 2;
#pragma unroll
        for (int half = 0; half < 2; ++half) {
            bf16x8 v;
#pragma unroll
            for (int c = 0; c < 8; ++c) v[c] = L[(half * 8 + c) * S2 + lane];
            *(bf16x8*)(hout + (size_t)(node0 + half) * 512 + lane * 8) = v;
        }
    } else {
        bf16x8 o0 = *(const bf16x8*)(L + r * S2 + 8 * g);
        *(bf16x8*)(hout + (size_t)(row0 + r) * OUT + 8 * g) = o0;
    }
}

// ---------------- rho: pool channels + 2-GEMM MLP, fp32 out ----------------
__global__ __launch_bounds__(256) void k_rho(
    const unsigned short* __restrict__ h2,
    const unsigned short* __restrict__ Wr1b, const float* __restrict__ br1,
    const unsigned short* __restrict__ Wr2b, const float* __restrict__ br2,
    float* __restrict__ out)
{
    constexpr int S = 72;
    __shared__ short lds[4][16 * S];
    int lane = threadIdx.x & 63, wid = threadIdx.x >> 6, g = lane >> 4, r = lane & 15;
    short* L = lds[wid];
    int tile = blockIdx.x * 4 + wid;      // 1250 tiles
    if (tile * 16 >= NN) return;
    bf16x8 w1f[4], w2f[2][4];
#pragma unroll
    for (int t = 0; t < 4; ++t) w1f[t] = load_bfrag(Wr1b, 64, 0, t * 16, lane);
#pragma unroll
    for (int kk = 0; kk < 2; ++kk)
#pragma unroll
        for (int t = 0; t < 4; ++t) w2f[kk][t] = load_bfrag(Wr2b, 64, kk * 32, t * 16, lane);
    float b1v[4], b2v[4];
#pragma unroll
    for (int t = 0; t < 4; ++t) { b1v[t] = br1[t * 16 + r]; b2v[t] = br2[t * 16 + r]; }

    int n = tile * 16 + r;
    float s[8] = {0.f, 0.f, 0.f, 0.f, 0.f, 0.f, 0.f, 0.f};
#pragma unroll
    for (int c = 0; c < NCH; ++c) {
        bf16x8 hv = *(const bf16x8*)(h2 + ((size_t)n * 8 + c) * 32 + 8 * g);
#pragma unroll
        for (int j = 0; j < 8; ++j) s[j] += b2f((unsigned short)hv[j]);
    }
    bf16x8 af;
#pragma unroll
    for (int j = 0; j < 8; ++j) af[j] = (short)f2b(s[j]);
    f32x4 c1[4];
#pragma unroll
    for (int t = 0; t < 4; ++t) {
        f32x4 c = {0.f, 0.f, 0.f, 0.f};
        c1[t] = mfma16(af, w1f[t], c);
    }
#pragma unroll
    for (int t = 0; t < 4; ++t)
#pragma unroll
        for (int i = 0; i < 4; ++i)
            L[(4 * g + i) * S + t * 16 + r] = (short)f2b(fmaxf(c1[t][i] + b1v[t], 0.f));
    asm volatile("" ::: "memory");
    bf16x8 t0 = *(const bf16x8*)(L + r * S + 8 * g);
    bf16x8 t1 = *(const bf16x8*)(L + r * S + 32 + 8 * g);
    f32x4 c2[4];
#pragma unroll
    for (int t = 0; t < 4; ++t) {
        f32x4 c = {0.f, 0.f, 0.f, 0.f};
        c = mfma16(t0, w2f[0][t], c);
        c = mfma16(t1, w2f[1][t], c);
        c2[t] = c;
    }
    int nb = tile * 16;
#pragma unroll
    for (int t = 0; t < 4; ++t)
#pragma unroll
        for (int i = 0; i < 4; ++i)
            out[(size_t)(nb + 4 * g + i) * 64 + t * 16 + r] = c2[t][i] + b2v[t];
}

extern "C" void kernel_launch(void* const* d_in, const int* in_sizes, int n_in,
                              void* d_out, int out_size, void* d_ws, size_t ws_size,
                              hipStream_t stream)
{
    const float* x   = (const float*)d_in[0];
    const float* ea  = (const float*)d_in[1];
    const int*   ei  = (const int*)d_in[2];
    const float* We0 = (const float*)d_in[3];
    const float* be0 = (const float*)d_in[4];
    const float* W10 = (const float*)d_in[5];
    const float* b10 = (const float*)d_in[6];
    const float* W20 = (const float*)d_in[7];
    const float* b20 = (const float*)d_in[8];
    const float* We1 = (const float*)d_in[9];
    const float* be1 = (const float*)d_in[10];
    const float* W11 = (const float*)d_in[11];
    const float* b11 = (const float*)d_in[12];
    const float* W21 = (const float*)d_in[13];
    const float* b21 = (const float*)d_in[14];
    const float* We2 = (const float*)d_in[15];
    const float* be2 = (const float*)d_in[16];
    const float* W12 = (const float*)d_in[17];
    const float* b12 = (const float*)d_in[18];
    const float* W22 = (const float*)d_in[19];
    const float* b22 = (const float*)d_in[20];
    const float* Wr1 = (const float*)d_in[21];
    const float* br1 = (const float*)d_in[22];
    const float* Wr2 = (const float*)d_in[23];
    const float* br2 = (const float*)d_in[24];
    float* out = (float*)d_out;

    // ---- workspace layout (128B-aligned blocks) ----
    char* base = (char*)d_ws;
    unsigned short* hT   = (unsigned short*)base; base += (size_t)NN * 512 * 2;        // 20.48 MB
    unsigned short* z    = (unsigned short*)base; base += (size_t)160000 * 64 * 2;     // 20.48 MB
    unsigned short* h2   = (unsigned short*)base; base += (size_t)160000 * 32 * 2;     // 10.24 MB
    unsigned short* eap  = (unsigned short*)base; base += (size_t)NE * 32 * 2;         // 40.96 MB
    float* emb0          = (float*)base;          base += (size_t)NE * 4;              //  2.56 MB
    float* z0            = (float*)base;          base += (size_t)160000 * 4;          //  0.64 MB
    float* xt            = (float*)base;          base += (size_t)NN * 4 * 4;          //  0.32 MB
    int* srcp            = (int*)base;            base += (size_t)NE * 4;              //  2.56 MB
    int* row             = (int*)base;            base += 80128;
    int* cnt             = (int*)base;            base += 80128;
    int* cursor          = (int*)base;            base += 80128;
    unsigned short* bw   = (unsigned short*)base;                                      // 57 KB

    const unsigned short* bWe1 = bw;
    const unsigned short* bWe2 = bw + 2048;
    const unsigned short* bW11 = bw + 4096;
    const unsigned short* bW21 = bw + 8192;
    const unsigned short* bW12 = bw + 12288;
    const unsigned short* bW22 = bw + 16384;
    const unsigned short* bW20 = bw + 18432;
    const unsigned short* bWr1 = bw + 22528;
    const unsigned short* bWr2 = bw + 24576;

    // ---- prep ----
    k_prep<<<112, 256, 0, stream>>>(We1, We2, W11, W21, W12, W22, W20, Wr1, Wr2, bw);
    hipMemsetAsync(cnt, 0, NN * sizeof(int), stream);
    k_hist<<<NE / 256, 256, 0, stream>>>(ei, cnt, x, xt);
    k_scan<<<1, 1024, 0, stream>>>(cnt, row, cursor);
    k_scatter2<<<NE / 256, 256, 0, stream>>>(ei, cursor, ea, We0, be0, srcp, eap, emb0);

    // ---- layer 0 ----
    k_l0_gather<<<(NN / 2 + 3) / 4, 256, 0, stream>>>(xt, srcp, row, emb0, z0);
    k_l0_mlp<<<2500, 256, 0, stream>>>(z0, W10, b10, bW20, b20, hT);

    // ---- layer 1 ----
    k_gather_f<<<NN / 4, 256, 0, stream>>>(srcp, row, eap, bWe1, be1, hT, z);
    k_mlp<64, true, true><<<2500, 256, 0, stream>>>(z, bW11, b11, bW21, b21, hT);

    // ---- layer 2 ----
    k_gather_f<<<NN / 4, 256, 0, stream>>>(srcp, row, eap, bWe2, be2, hT, z);
    k_mlp<32, false, false><<<2500, 256, 0, stream>>>(z, bW12, b12, bW22, b22, h2);

    // ---- pool + rho ----
    k_rho<<<313, 256, 0, stream>>>(h2, bWr1, br1, bWr2, br2, out);
}

// Round 12
// 354.429 us; speedup vs baseline: 1.1062x; 1.0103x over previous
//
#include <hip/hip_runtime.h>

#define NN 20000
#define NE 640000
#define NCH 8
#define HID 64
#define EDIM 32
#define ODIM 64

typedef __attribute__((ext_vector_type(8))) short bf16x8;
typedef __attribute__((ext_vector_type(4))) float f32x4;

__device__ __forceinline__ float b2f(unsigned short u) {
    unsigned v = ((unsigned)u) << 16;
    return __builtin_bit_cast(float, v);
}
__device__ __forceinline__ unsigned short f2b(float f) {   // RNE
    unsigned u = __builtin_bit_cast(unsigned, f);
    unsigned r = (u + 0x7fffu + ((u >> 16) & 1u)) >> 16;
    return (unsigned short)r;
}
__device__ __forceinline__ f32x4 mfma16(bf16x8 a, bf16x8 b, f32x4 c) {
    return __builtin_amdgcn_mfma_f32_16x16x32_bf16(a, b, c, 0, 0, 0);
}
// B-fragment: lane(g=l>>4, r=l&15) holds B[k0+8g+j][n0+r], W row-major [K][ldn]
__device__ __forceinline__ bf16x8 load_bfrag(const unsigned short* W, int ldn, int k0, int n0, int lane) {
    int g = lane >> 4, r = lane & 15;
    bf16x8 f;
#pragma unroll
    for (int j = 0; j < 8; ++j) f[j] = (short)W[(k0 + 8 * g + j) * ldn + n0 + r];
    return f;
}

// ---------------- fused prep: weight cast + histogram + x transpose ----------------
__global__ __launch_bounds__(256) void k_prep_hist(
    const float* We1, const float* We2, const float* W11, const float* W21,
    const float* W12, const float* W22, const float* W20, const float* Wr1,
    const float* Wr2, unsigned short* bw,
    const int* __restrict__ ei, int* __restrict__ cnt,
    const float* __restrict__ x, float* __restrict__ xt)
{
    int gid = blockIdx.x * 256 + threadIdx.x;
    if (gid < NE) atomicAdd(&cnt[ei[NE + gid]], 1);
    if (gid < NN) {
        f32x4 v = {x[gid], x[NN + gid], x[2 * NN + gid], x[3 * NN + gid]};
        *(f32x4*)(xt + (size_t)gid * 4) = v;
    }
    if (gid < 28672) {   // total weight elements (R11 bug: was 25088, truncated Wr2)
        const float* src; int off;
        if      (gid < 2048)  { src = We1; off = 0; }
        else if (gid < 4096)  { src = We2; off = 2048; }
        else if (gid < 8192)  { src = W11; off = 4096; }
        else if (gid < 12288) { src = W21; off = 8192; }
        else if (gid < 16384) { src = W12; off = 12288; }
        else if (gid < 18432) { src = W22; off = 16384; }
        else if (gid < 22528) { src = W20; off = 18432; }
        else if (gid < 24576) { src = Wr1; off = 22528; }
        else                  { src = Wr2; off = 24576; }
        bw[gid] = f2b(src[gid - off]);
    }
}

__global__ __launch_bounds__(1024) void k_scan(const int* __restrict__ cnt,
                                               int* __restrict__ row, int* __restrict__ cursor)
{
    __shared__ int part[1024];
    int t = threadIdx.x;
    int base = t * 20;                  // 1024*20 = 20480 >= 20000
    int s = 0;
#pragma unroll
    for (int i = 0; i < 20; ++i) { int idx = base + i; if (idx < NN) s += cnt[idx]; }
    part[t] = s;
    __syncthreads();
    int v = s;
    for (int off = 1; off < 1024; off <<= 1) {
        int add = (t >= off) ? part[t - off] : 0;
        __syncthreads();
        v += add;
        part[t] = v;
        __syncthreads();
    }
    int run = v - s;
    for (int i = 0; i < 20; ++i) {
        int idx = base + i;
        if (idx < NN) { row[idx] = run; cursor[idx] = run; run += cnt[idx]; }
    }
    if (t == 1023) row[NN] = NE;
}

// ---------------- scatter + ea permute + layer-0 scalar embed (fused) ----------------
__global__ __launch_bounds__(256) void k_scatter2(
    const int* __restrict__ ei, int* __restrict__ cursor,
    const float* __restrict__ ea, const float* __restrict__ We0, const float* __restrict__ be0,
    int* __restrict__ srcp, unsigned short* __restrict__ eap, float* __restrict__ emb0)
{
    int e = blockIdx.x * 256 + threadIdx.x;
    if (e >= NE) return;
    int d = ei[NE + e];
    int pos = atomicAdd(&cursor[d], 1);
    srcp[pos] = ei[e];
    const f32x4* s4 = (const f32x4*)(ea + (size_t)e * 32);   // sequential read
    float e0 = be0[0];
#pragma unroll
    for (int h = 0; h < 4; ++h) {
        f32x4 a = s4[2 * h], b = s4[2 * h + 1];
        bf16x8 o;
#pragma unroll
        for (int j = 0; j < 4; ++j) {
            e0 = fmaf(a[j], We0[h * 8 + j], e0);
            e0 = fmaf(b[j], We0[h * 8 + 4 + j], e0);
            o[j] = (short)f2b(a[j]);
            o[4 + j] = (short)f2b(b[j]);
        }
        *(bf16x8*)(eap + (size_t)pos * 32 + h * 8) = o;      // scattered 64B write
    }
    emb0[pos] = e0;
}

// ---------------- layer 0 fused: gather (wave = 2 nodes) + MLP tile -> hT ----------------
__global__ __launch_bounds__(256) void k_l0_fused(
    const float* __restrict__ xt, const int* __restrict__ srcp,
    const int* __restrict__ row, const float* __restrict__ emb0,
    const float* __restrict__ W1, const float* __restrict__ b1,
    const unsigned short* __restrict__ W2b, const float* __restrict__ b2,
    unsigned short* __restrict__ hT)
{
    constexpr int S = 72;
    __shared__ float zrow[4][16];
    __shared__ short lds[4][16 * S];
    int lane = threadIdx.x & 63, wid = threadIdx.x >> 6, g = lane >> 4, r = lane & 15;
    int gw = blockIdx.x * 4 + wid;           // 10000 waves, 2 nodes each
    int halfq = lane >> 5, l = lane & 31;
    int d = gw * 2 + halfq;

    // ---- phase 1: edge gather (32 lanes per node) ----
    int p0 = row[d], p1 = row[d + 1];
    float ap0 = 0.f, ap1 = 0.f, ap2 = 0.f, ap3 = 0.f;
    float am0 = 0.f, am1 = 0.f, am2 = 0.f, am3 = 0.f;
    for (int p = p0 + l; p < p1; p += 32) {
        float e0 = emb0[p];
        f32x4 xs = *(const f32x4*)(xt + (size_t)srcp[p] * 4);
        ap0 += fmaxf(xs[0] + e0, 0.f); am0 += fmaxf(e0 - xs[0], 0.f);
        ap1 += fmaxf(xs[1] + e0, 0.f); am1 += fmaxf(e0 - xs[1], 0.f);
        ap2 += fmaxf(xs[2] + e0, 0.f); am2 += fmaxf(e0 - xs[2], 0.f);
        ap3 += fmaxf(xs[3] + e0, 0.f); am3 += fmaxf(e0 - xs[3], 0.f);
    }
#pragma unroll
    for (int off = 1; off < 32; off <<= 1) {
        ap0 += __shfl_xor(ap0, off, 64); am0 += __shfl_xor(am0, off, 64);
        ap1 += __shfl_xor(ap1, off, 64); am1 += __shfl_xor(am1, off, 64);
        ap2 += __shfl_xor(ap2, off, 64); am2 += __shfl_xor(am2, off, 64);
        ap3 += __shfl_xor(ap3, off, 64); am3 += __shfl_xor(am3, off, 64);
    }
    if (l == 0) {
        f32x4 xd = *(const f32x4*)(xt + (size_t)d * 4);
        zrow[wid][halfq * 8 + 0] = xd[0] + ap0;
        zrow[wid][halfq * 8 + 1] = xd[1] + ap1;
        zrow[wid][halfq * 8 + 2] = xd[2] + ap2;
        zrow[wid][halfq * 8 + 3] = xd[3] + ap3;
        zrow[wid][halfq * 8 + 4] = am0 - xd[0];
        zrow[wid][halfq * 8 + 5] = am1 - xd[1];
        zrow[wid][halfq * 8 + 6] = am2 - xd[2];
        zrow[wid][halfq * 8 + 7] = am3 - xd[3];
    }
    asm volatile("" ::: "memory");
    __builtin_amdgcn_sched_barrier(0);

    // ---- phase 2: MLP tile (rows = this wave's 2 nodes x 8 ch) ----
    float zv = zrow[wid][r];
    short* L = lds[wid];
    bf16x8 w2f[2][4];
#pragma unroll
    for (int kk = 0; kk < 2; ++kk)
#pragma unroll
        for (int t = 0; t < 4; ++t) w2f[kk][t] = load_bfrag(W2b, 64, kk * 32, t * 16, lane);
    float b2v[4];
#pragma unroll
    for (int t = 0; t < 4; ++t) b2v[t] = b2[t * 16 + r];
    float w1a[8], w1b[8], b1a[8], b1b[8];
#pragma unroll
    for (int j = 0; j < 8; ++j) {
        w1a[j] = W1[8 * g + j];      b1a[j] = b1[8 * g + j];
        w1b[j] = W1[32 + 8 * g + j]; b1b[j] = b1[32 + 8 * g + j];
    }
    bf16x8 a0, a1;
#pragma unroll
    for (int j = 0; j < 8; ++j) {
        a0[j] = (short)f2b(fmaxf(fmaf(zv, w1a[j], b1a[j]), 0.f));
        a1[j] = (short)f2b(fmaxf(fmaf(zv, w1b[j], b1b[j]), 0.f));
    }
    f32x4 c2[4];
#pragma unroll
    for (int t = 0; t < 4; ++t) {
        f32x4 c = {0.f, 0.f, 0.f, 0.f};
        c = mfma16(a0, w2f[0][t], c);
        c = mfma16(a1, w2f[1][t], c);
        c2[t] = c;
    }
#pragma unroll
    for (int t = 0; t < 4; ++t)
#pragma unroll
        for (int i = 0; i < 4; ++i)
            L[(4 * g + i) * S + t * 16 + r] = (short)f2b(fmaxf(c2[t][i] + b2v[t], 0.f));
    asm volatile("" ::: "memory");
    int node0 = gw * 2;
#pragma unroll
    for (int half = 0; half < 2; ++half) {
        bf16x8 v;
#pragma unroll
        for (int c = 0; c < 8; ++c) v[c] = L[(half * 8 + c) * S + lane];
        *(bf16x8*)(hT + (size_t)(node0 + half) * 512 + lane * 8) = v;
    }
}

// ---------------- fused gather: We fragments staged in LDS (low VGPR), 4-deep batches ----------------
__global__ __launch_bounds__(256) void k_gather_f(
    const int* __restrict__ srcp, const int* __restrict__ row,
    const unsigned short* __restrict__ eap,
    const unsigned short* __restrict__ Web, const float* __restrict__ be,
    const unsigned short* __restrict__ hT, unsigned short* __restrict__ z)
{
    constexpr int SE = 66;                  // em tile stride (shorts)
    __shared__ short Lw[4 * 64 * 8];        // fragmentized We: tile t, lane l -> 8 shorts
    __shared__ short Lem[4][16 * SE];       // per-wave em tile (bf16)
    int lane = threadIdx.x & 63, wid = threadIdx.x >> 6, g = lane >> 4, r = lane & 15;
    short* Le = Lem[wid];

    // stage We fragments once per block: wave wid handles tile wid
    {
        bf16x8 f = load_bfrag(Web, 64, 0, wid * 16, lane);
        *(bf16x8*)(Lw + (wid * 64 + lane) * 8) = f;
    }
    float bev[4];
#pragma unroll
    for (int t = 0; t < 4; ++t) bev[t] = be[t * 16 + r];
    __syncthreads();

    int d = blockIdx.x * 4 + wid;     // 5000 blocks x 4 waves = 20000
    int p0 = row[d], p1 = row[d + 1];
    float acc[NCH];
#pragma unroll
    for (int c = 0; c < NCH; ++c) acc[c] = 0.f;

    for (int p = p0; p < p1; p += 16) {
        int ne = p1 - p; if (ne > 16) ne = 16;
        int pp = p + r; if (pp > p1 - 1) pp = p1 - 1;
        bf16x8 afc = *(const bf16x8*)(eap + (size_t)pp * 32 + 8 * g);
        int svc = srcp[pp];
#pragma unroll
        for (int t = 0; t < 4; ++t) {
            bf16x8 wfrag = *(const bf16x8*)(Lw + (t * 64 + lane) * 8);
            f32x4 cc = {bev[t], bev[t], bev[t], bev[t]};
            cc = mfma16(afc, wfrag, cc);
#pragma unroll
            for (int i = 0; i < 4; ++i) {
                unsigned short v = (4 * g + i < ne) ? f2b(cc[i]) : (unsigned short)0xFF80; // bf16 -inf
                Le[(4 * g + i) * SE + t * 16 + r] = (short)v;
            }
        }
        asm volatile("" ::: "memory");
#pragma unroll
        for (int b = 0; b < 4; ++b) {
#pragma unroll
            for (int q = 4 * b; q < 4 * b + 4; ++q) {
                int src = __builtin_amdgcn_readlane(svc, q);
                float em = b2f((unsigned short)Le[q * SE + lane]);
                uint4 hv = *(const uint4*)(hT + (size_t)src * 512 + (lane << 3));
                acc[0] += fmaxf(__builtin_bit_cast(float, hv.x << 16) + em, 0.f);
                acc[1] += fmaxf(__builtin_bit_cast(float, hv.x & 0xffff0000u) + em, 0.f);
                acc[2] += fmaxf(__builtin_bit_cast(float, hv.y << 16) + em, 0.f);
                acc[3] += fmaxf(__builtin_bit_cast(float, hv.y & 0xffff0000u) + em, 0.f);
                acc[4] += fmaxf(__builtin_bit_cast(float, hv.z << 16) + em, 0.f);
                acc[5] += fmaxf(__builtin_bit_cast(float, hv.z & 0xffff0000u) + em, 0.f);
                acc[6] += fmaxf(__builtin_bit_cast(float, hv.w << 16) + em, 0.f);
                acc[7] += fmaxf(__builtin_bit_cast(float, hv.w & 0xffff0000u) + em, 0.f);
            }
            __builtin_amdgcn_sched_barrier(0);
        }
        asm volatile("" ::: "memory");
    }

    // epilogue: z = h_dst + acc
    uint4 hd = *(const uint4*)(hT + (size_t)d * 512 + (lane << 3));
    unsigned hw[4] = {hd.x, hd.y, hd.z, hd.w};
    unsigned short* zd = z + (size_t)d * 8 * 64 + lane;
#pragma unroll
    for (int j = 0; j < 4; ++j) {
        float lo = __builtin_bit_cast(float, hw[j] << 16);
        float hi = __builtin_bit_cast(float, hw[j] & 0xffff0000u);
        zd[(2 * j) * 64] = f2b(lo + acc[2 * j]);
        zd[(2 * j + 1) * 64] = f2b(hi + acc[2 * j + 1]);
    }
}

// ---------------- node MLP 64->64 (layer 1): z -> hT ----------------
__global__ __launch_bounds__(256) void k_mlp64(
    const unsigned short* __restrict__ z,
    const unsigned short* __restrict__ W1b, const float* __restrict__ b1,
    const unsigned short* __restrict__ W2b, const float* __restrict__ b2,
    unsigned short* __restrict__ hout)
{
    constexpr int S1 = 72;
    __shared__ short lds[4][16 * S1];
    int lane = threadIdx.x & 63, wid = threadIdx.x >> 6, g = lane >> 4, r = lane & 15;
    short* L = lds[wid];

    bf16x8 w1f[2][4], w2f[2][4];
#pragma unroll
    for (int kk = 0; kk < 2; ++kk)
#pragma unroll
        for (int t = 0; t < 4; ++t) {
            w1f[kk][t] = load_bfrag(W1b, 64, kk * 32, t * 16, lane);
            w2f[kk][t] = load_bfrag(W2b, 64, kk * 32, t * 16, lane);
        }
    float b1v[4], b2v[4];
#pragma unroll
    for (int t = 0; t < 4; ++t) { b1v[t] = b1[t * 16 + r]; b2v[t] = b2[t * 16 + r]; }

    int tile = blockIdx.x * 4 + wid;      // 10000 tiles
    int row0 = tile * 16;

    bf16x8 a0 = *(const bf16x8*)(z + (size_t)(row0 + r) * 64 + 8 * g);
    bf16x8 a1 = *(const bf16x8*)(z + (size_t)(row0 + r) * 64 + 32 + 8 * g);
    f32x4 c1[4];
#pragma unroll
    for (int t = 0; t < 4; ++t) {
        f32x4 c = {0.f, 0.f, 0.f, 0.f};
        c = mfma16(a0, w1f[0][t], c);
        c = mfma16(a1, w1f[1][t], c);
        c1[t] = c;
    }
#pragma unroll
    for (int t = 0; t < 4; ++t)
#pragma unroll
        for (int i = 0; i < 4; ++i)
            L[(4 * g + i) * S1 + t * 16 + r] = (short)f2b(fmaxf(c1[t][i] + b1v[t], 0.f));
    asm volatile("" ::: "memory");
    bf16x8 t0 = *(const bf16x8*)(L + r * S1 + 8 * g);
    bf16x8 t1 = *(const bf16x8*)(L + r * S1 + 32 + 8 * g);
    f32x4 c2[4];
#pragma unroll
    for (int t = 0; t < 4; ++t) {
        f32x4 c = {0.f, 0.f, 0.f, 0.f};
        c = mfma16(t0, w2f[0][t], c);
        c = mfma16(t1, w2f[1][t], c);
        c2[t] = c;
    }
    asm volatile("" ::: "memory");
#pragma unroll
    for (int t = 0; t < 4; ++t)
#pragma unroll
        for (int i = 0; i < 4; ++i)
            L[(4 * g + i) * S1 + t * 16 + r] = (short)f2b(fmaxf(c2[t][i] + b2v[t], 0.f));  // inter-layer relu
    asm volatile("" ::: "memory");
    int node0 = tile * 2;
#pragma unroll
    for (int half = 0; half < 2; ++half) {
        bf16x8 v;
#pragma unroll
        for (int c = 0; c < 8; ++c) v[c] = L[(half * 8 + c) * S1 + lane];
        *(bf16x8*)(hout + (size_t)(node0 + half) * 512 + lane * 8) = v;
    }
}

// ---------------- layer-2 MLP (64->64->32) + channel pool + rho (32->64->64) -> out ----------------
__global__ __launch_bounds__(256) void k_mlp_rho(
    const unsigned short* __restrict__ z,
    const unsigned short* __restrict__ W1b, const float* __restrict__ b1,
    const unsigned short* __restrict__ W2b, const float* __restrict__ b2,
    const unsigned short* __restrict__ Wr1b, const float* __restrict__ br1,
    const unsigned short* __restrict__ Wr2b, const float* __restrict__ br2,
    float* __restrict__ out)
{
    constexpr int S1 = 72, S2 = 40;
    __shared__ short lds[4][16 * S1];
    int lane = threadIdx.x & 63, wid = threadIdx.x >> 6, g = lane >> 4, r = lane & 15;
    short* L = lds[wid];

    bf16x8 w1f[2][4], w2f[2][2];
#pragma unroll
    for (int kk = 0; kk < 2; ++kk) {
#pragma unroll
        for (int t = 0; t < 4; ++t) w1f[kk][t] = load_bfrag(W1b, 64, kk * 32, t * 16, lane);
#pragma unroll
        for (int t = 0; t < 2; ++t) w2f[kk][t] = load_bfrag(W2b, 32, kk * 32, t * 16, lane);
    }
    float b1v[4], b2v[2];
#pragma unroll
    for (int t = 0; t < 4; ++t) b1v[t] = b1[t * 16 + r];
#pragma unroll
    for (int t = 0; t < 2; ++t) b2v[t] = b2[t * 16 + r];

    int tile = blockIdx.x * 4 + wid;      // 10000 tiles = 2 nodes each
    int row0 = tile * 16;

    // GEMM1: z (16x64) @ W1 (64x64) -> relu
    bf16x8 a0 = *(const bf16x8*)(z + (size_t)(row0 + r) * 64 + 8 * g);
    bf16x8 a1 = *(const bf16x8*)(z + (size_t)(row0 + r) * 64 + 32 + 8 * g);
    f32x4 c1[4];
#pragma unroll
    for (int t = 0; t < 4; ++t) {
        f32x4 c = {0.f, 0.f, 0.f, 0.f};
        c = mfma16(a0, w1f[0][t], c);
        c = mfma16(a1, w1f[1][t], c);
        c1[t] = c;
    }
#pragma unroll
    for (int t = 0; t < 4; ++t)
#pragma unroll
        for (int i = 0; i < 4; ++i)
            L[(4 * g + i) * S1 + t * 16 + r] = (short)f2b(fmaxf(c1[t][i] + b1v[t], 0.f));
    asm volatile("" ::: "memory");
    bf16x8 t0 = *(const bf16x8*)(L + r * S1 + 8 * g);
    bf16x8 t1 = *(const bf16x8*)(L + r * S1 + 32 + 8 * g);
    // GEMM2 -> 16x32 (no relu), stage bf16
    f32x4 c2[2];
#pragma unroll
    for (int t = 0; t < 2; ++t) {
        f32x4 c = {0.f, 0.f, 0.f, 0.f};
        c = mfma16(t0, w2f[0][t], c);
        c = mfma16(t1, w2f[1][t], c);
        c2[t] = c;
    }
    asm volatile("" ::: "memory");
#pragma unroll
    for (int t = 0; t < 2; ++t)
#pragma unroll
        for (int i = 0; i < 4; ++i)
            L[(4 * g + i) * S2 + t * 16 + r] = (short)f2b(c2[t][i] + b2v[t]);
    asm volatile("" ::: "memory");

    // ---- pool: rows 0-7 -> node0, 8-15 -> node1; A-frag rows 0,1 hold pooled vectors ----
    bf16x8 af = {0, 0, 0, 0, 0, 0, 0, 0};
    if (r < 2) {
#pragma unroll
        for (int j = 0; j < 8; ++j) {
            float s = 0.f;
#pragma unroll
            for (int c = 0; c < 8; ++c) s += b2f((unsigned short)L[(r * 8 + c) * S2 + 8 * g + j]);
            af[j] = (short)f2b(s);
        }
    }
    asm volatile("" ::: "memory");

    // rho GEMM1: pooled (2x32) @ Wr1 (32x64) + br1 -> relu
    f32x4 c1r[4];
#pragma unroll
    for (int t = 0; t < 4; ++t) {
        bf16x8 wf = load_bfrag(Wr1b, 64, 0, t * 16, lane);
        float bb = br1[t * 16 + r];
        f32x4 cc = {bb, bb, bb, bb};
        c1r[t] = mfma16(af, wf, cc);
    }
#pragma unroll
    for (int t = 0; t < 4; ++t)
#pragma unroll
        for (int i = 0; i < 4; ++i)
            L[(4 * g + i) * S1 + t * 16 + r] = (short)f2b(fmaxf(c1r[t][i], 0.f));
    asm volatile("" ::: "memory");
    bf16x8 t0r = *(const bf16x8*)(L + r * S1 + 8 * g);
    bf16x8 t1r = *(const bf16x8*)(L + r * S1 + 32 + 8 * g);
    // rho GEMM2: (2x64) @ Wr2 (64x64) + br2 -> out rows {node0, node1}
    f32x4 c2r[4];
#pragma unroll
    for (int t = 0; t < 4; ++t) {
        float bb = br2[t * 16 + r];
        f32x4 cc = {bb, bb, bb, bb};
        cc = mfma16(t0r, load_bfrag(Wr2b, 64, 0, t * 16, lane), cc);
        cc = mfma16(t1r, load_bfrag(Wr2b, 64, 32, t * 16, lane), cc);
        c2r[t] = cc;
    }
    if (g == 0) {
        int node0 = tile * 2;
#pragma unroll
        for (int t = 0; t < 4; ++t) {
#pragma unroll
            for (int i = 0; i < 2; ++i)
                out[(size_t)(node0 + i) * 64 + t * 16 + r] = c2r[t][i];
        }
    }
}

extern "C" void kernel_launch(void* const* d_in, const int* in_sizes, int n_in,
                              void* d_out, int out_size, void* d_ws, size_t ws_size,
                              hipStream_t stream)
{
    const float* x   = (const float*)d_in[0];
    const float* ea  = (const float*)d_in[1];
    const int*   ei  = (const int*)d_in[2];
    const float* We0 = (const float*)d_in[3];
    const float* be0 = (const float*)d_in[4];
    const float* W10 = (const float*)d_in[5];
    const float* b10 = (const float*)d_in[6];
    const float* W20 = (const float*)d_in[7];
    const float* b20 = (const float*)d_in[8];
    const float* We1 = (const float*)d_in[9];
    const float* be1 = (const float*)d_in[10];
    const float* W11 = (const float*)d_in[11];
    const float* b11 = (const float*)d_in[12];
    const float* W21 = (const float*)d_in[13];
    const float* b21 = (const float*)d_in[14];
    const float* We2 = (const float*)d_in[15];
    const float* be2 = (const float*)d_in[16];
    const float* W12 = (const float*)d_in[17];
    const float* b12 = (const float*)d_in[18];
    const float* W22 = (const float*)d_in[19];
    const float* b22 = (const float*)d_in[20];
    const float* Wr1 = (const float*)d_in[21];
    const float* br1 = (const float*)d_in[22];
    const float* Wr2 = (const float*)d_in[23];
    const float* br2 = (const float*)d_in[24];
    float* out = (float*)d_out;

    // ---- workspace layout (128B-aligned blocks) ----
    char* base = (char*)d_ws;
    unsigned short* hT   = (unsigned short*)base; base += (size_t)NN * 512 * 2;        // 20.48 MB
    unsigned short* z    = (unsigned short*)base; base += (size_t)160000 * 64 * 2;     // 20.48 MB
    unsigned short* eap  = (unsigned short*)base; base += (size_t)NE * 32 * 2;         // 40.96 MB
    float* emb0          = (float*)base;          base += (size_t)NE * 4;              //  2.56 MB
    float* xt            = (float*)base;          base += (size_t)NN * 4 * 4;          //  0.32 MB
    int* srcp            = (int*)base;            base += (size_t)NE * 4;              //  2.56 MB
    int* row             = (int*)base;            base += 80128;
    int* cnt             = (int*)base;            base += 80128;
    int* cursor          = (int*)base;            base += 80128;
    unsigned short* bw   = (unsigned short*)base;                                      // 57 KB

    const unsigned short* bWe1 = bw;
    const unsigned short* bWe2 = bw + 2048;
    const unsigned short* bW11 = bw + 4096;
    const unsigned short* bW21 = bw + 8192;
    const unsigned short* bW12 = bw + 12288;
    const unsigned short* bW22 = bw + 16384;
    const unsigned short* bW20 = bw + 18432;
    const unsigned short* bWr1 = bw + 22528;
    const unsigned short* bWr2 = bw + 24576;

    // ---- prep (fused) ----
    hipMemsetAsync(cnt, 0, NN * sizeof(int), stream);
    k_prep_hist<<<NE / 256, 256, 0, stream>>>(We1, We2, W11, W21, W12, W22, W20, Wr1, Wr2,
                                              bw, ei, cnt, x, xt);
    k_scan<<<1, 1024, 0, stream>>>(cnt, row, cursor);
    k_scatter2<<<NE / 256, 256, 0, stream>>>(ei, cursor, ea, We0, be0, srcp, eap, emb0);

    // ---- layer 0 (gather + MLP fused) ----
    k_l0_fused<<<2500, 256, 0, stream>>>(xt, srcp, row, emb0, W10, b10, bW20, b20, hT);

    // ---- layer 1 ----
    k_gather_f<<<NN / 4, 256, 0, stream>>>(srcp, row, eap, bWe1, be1, hT, z);
    k_mlp64<<<2500, 256, 0, stream>>>(z, bW11, b11, bW21, b21, hT);

    // ---- layer 2 (MLP + pool + rho fused) ----
    k_gather_f<<<NN / 4, 256, 0, stream>>>(srcp, row, eap, bWe2, be2, hT, z);
    k_mlp_rho<<<2500, 256, 0, stream>>>(z, bW12, b12, bW22, b22, bWr1, br1, bWr2, br2, out);
}